// Round 15
// baseline (766.222 us; speedup 1.0000x reference)
//
#include <hip/hip_runtime.h>
#include <hip/hip_bf16.h>
#include <stdint.h>

#define TT 1024
#define EE 1024
#define HH 16
#define DD 64
#define BHN 32
#define HB 153
#define RECW 102
#define RING2 8
#define INFLT2 6
#define NEGF (-3.4028234663852886e38f)

typedef unsigned long long ull;
typedef __attribute__((ext_vector_type(8))) short bf16x8;
typedef __attribute__((ext_vector_type(4))) float f32x4;
typedef __attribute__((address_space(3))) float lds_float;

// workspace layout (float element offsets)
#define OFF_Q  ((size_t)0)
#define OFF_K  (OFF_Q + (size_t)BHN*TT*DD)
#define OFF_V  (OFF_K + (size_t)BHN*TT*DD)   // reused as bf16 (ushort) buffer
#define OFF_AW (OFF_V + (size_t)BHN*TT*DD)
#define OFF_M  (OFF_AW + (size_t)BHN*TT*TT)
#define OFF_S  (OFF_M + (size_t)BHN*TT)
#define OFF_AO (OFF_S + (size_t)BHN*TT)
#define OFF_END (OFF_AO + (size_t)BHN*TT*DD)
// after OFF_END: initacc float[BHN*256], evict int[BHN*1024]

__device__ __forceinline__ ushort f2bf(float x) {
  unsigned u = __float_as_uint(x);
  u = (u + 0x7FFF + ((u >> 16) & 1)) >> 16;   // RNE
  return (ushort)u;
}
__device__ __forceinline__ float bf2f(ushort h) {
  return __uint_as_float((unsigned)h << 16);
}

// ---------------- split-bf16 MFMA GEMM: Y = (X @ W + b) * scale
// mode: 0 = flat f32, 1 = headsplit f32, 2 = headsplit bf16
__global__ __launch_bounds__(256) void k_pmm(const float* __restrict__ X,
    const float* __restrict__ W, const float* __restrict__ bias,
    float* __restrict__ Y, float scale, int mode) {
  __shared__ ushort Ah[64][72], Al[64][72];   // X tile hi/lo: [row][k]
  __shared__ ushort Bh[64][72], Bl[64][72];   // W tile hi/lo TRANSPOSED: [col][k]
  int tid = threadIdx.x, lane = tid & 63, wid = tid >> 6;
  int r = tid >> 2, c0 = (tid & 3) * 16;
  int r0 = blockIdx.y * 64, n0 = blockIdx.x * 64;

  f32x4 acc[4];
  #pragma unroll
  for (int nc = 0; nc < 4; ++nc) acc[nc] = (f32x4){0.f, 0.f, 0.f, 0.f};

  for (int k0 = 0; k0 < EE; k0 += 64) {
    __syncthreads();
    {
      const float4* xs = (const float4*)(X + (size_t)(r0 + r) * EE + k0 + c0);
      #pragma unroll
      for (int q4 = 0; q4 < 4; ++q4) {
        float4 v = xs[q4];
        float f[4] = {v.x, v.y, v.z, v.w};
        ushort hi[4], lo[4];
        #pragma unroll
        for (int u = 0; u < 4; ++u) {
          hi[u] = f2bf(f[u]);
          lo[u] = f2bf(f[u] - bf2f(hi[u]));
        }
        *(unsigned*)&Ah[r][c0 + q4*4]     = (unsigned)hi[0] | ((unsigned)hi[1] << 16);
        *(unsigned*)&Ah[r][c0 + q4*4 + 2] = (unsigned)hi[2] | ((unsigned)hi[3] << 16);
        *(unsigned*)&Al[r][c0 + q4*4]     = (unsigned)lo[0] | ((unsigned)lo[1] << 16);
        *(unsigned*)&Al[r][c0 + q4*4 + 2] = (unsigned)lo[2] | ((unsigned)lo[3] << 16);
      }
    }
    {
      const float4* wsrc = (const float4*)(W + (size_t)(k0 + r) * EE + n0 + c0);
      #pragma unroll
      for (int q4 = 0; q4 < 4; ++q4) {
        float4 v = wsrc[q4];
        float f[4] = {v.x, v.y, v.z, v.w};
        #pragma unroll
        for (int u = 0; u < 4; ++u) {
          ushort hi = f2bf(f[u]);
          ushort lo = f2bf(f[u] - bf2f(hi));
          int c = c0 + q4*4 + u;
          Bh[c][r] = hi;
          Bl[c][r] = lo;
        }
      }
    }
    __syncthreads();
    #pragma unroll
    for (int kb = 0; kb < 2; ++kb) {
      bf16x8 ah = *(const bf16x8*)&Ah[wid*16 + (lane & 15)][kb*32 + (lane >> 4)*8];
      bf16x8 al = *(const bf16x8*)&Al[wid*16 + (lane & 15)][kb*32 + (lane >> 4)*8];
      #pragma unroll
      for (int nc = 0; nc < 4; ++nc) {
        bf16x8 bh_ = *(const bf16x8*)&Bh[nc*16 + (lane & 15)][kb*32 + (lane >> 4)*8];
        bf16x8 bl_ = *(const bf16x8*)&Bl[nc*16 + (lane & 15)][kb*32 + (lane >> 4)*8];
        acc[nc] = __builtin_amdgcn_mfma_f32_16x16x32_bf16(ah, bh_, acc[nc], 0, 0, 0);
        acc[nc] = __builtin_amdgcn_mfma_f32_16x16x32_bf16(al, bh_, acc[nc], 0, 0, 0);
        acc[nc] = __builtin_amdgcn_mfma_f32_16x16x32_bf16(ah, bl_, acc[nc], 0, 0, 0);
      }
    }
  }

  int rowbase = wid*16 + (lane >> 4)*4;
  #pragma unroll
  for (int nc = 0; nc < 4; ++nc) {
    int c = n0 + nc*16 + (lane & 15);
    float bv = bias[c];
    #pragma unroll
    for (int qq = 0; qq < 4; ++qq) {
      int rr = r0 + rowbase + qq;
      float val = (acc[nc][qq] + bv) * scale;
      int b_ = rr >> 10, t_ = rr & 1023, h_ = c >> 6, d_ = c & 63;
      if (mode == 1) {
        Y[(((size_t)(b_*HH + h_) * TT) + t_) * DD + d_] = val;
      } else if (mode == 2) {
        ((ushort*)Y)[(((size_t)(b_*HH + h_) * TT) + t_) * DD + d_] = f2bf(val);
      } else {
        Y[(size_t)rr * EE + c] = val;
      }
    }
  }
}

// ---------------- batched QK^T via split-bf16 MFMA (lower-triangle tiles)
__global__ __launch_bounds__(256) void k_qk_mfma(const float* __restrict__ q,
    const float* __restrict__ k, float* __restrict__ aw) {
  int bh = blockIdx.y, tt = blockIdx.x;
  int t0 = tt * 64;
  int tid = threadIdx.x, lane = tid & 63, wid = tid >> 6;
  int r = tid >> 2, c0 = (tid & 3) * 16;
  __shared__ ushort Qh[64][72], Ql[64][72];
  __shared__ ushort Kh[64][72], Kl[64][72];
  const float* qb = q + (size_t)bh * TT * DD;
  const float* kb = k + (size_t)bh * TT * DD;
  float* awb = aw + (size_t)bh * TT * TT;

  {
    const float4* xs = (const float4*)(qb + (size_t)(t0 + r) * DD + c0);
    #pragma unroll
    for (int q4 = 0; q4 < 4; ++q4) {
      float4 v = xs[q4];
      float f[4] = {v.x, v.y, v.z, v.w};
      ushort hi[4], lo[4];
      #pragma unroll
      for (int u = 0; u < 4; ++u) {
        hi[u] = f2bf(f[u]);
        lo[u] = f2bf(f[u] - bf2f(hi[u]));
      }
      *(unsigned*)&Qh[r][c0 + q4*4]     = (unsigned)hi[0] | ((unsigned)hi[1] << 16);
      *(unsigned*)&Qh[r][c0 + q4*4 + 2] = (unsigned)hi[2] | ((unsigned)hi[3] << 16);
      *(unsigned*)&Ql[r][c0 + q4*4]     = (unsigned)lo[0] | ((unsigned)lo[1] << 16);
      *(unsigned*)&Ql[r][c0 + q4*4 + 2] = (unsigned)lo[2] | ((unsigned)lo[3] << 16);
    }
  }

  for (int st = 0; st <= tt; ++st) {
    __syncthreads();
    {
      const float4* xs = (const float4*)(kb + (size_t)(st * 64 + r) * DD + c0);
      #pragma unroll
      for (int q4 = 0; q4 < 4; ++q4) {
        float4 v = xs[q4];
        float f[4] = {v.x, v.y, v.z, v.w};
        ushort hi[4], lo[4];
        #pragma unroll
        for (int u = 0; u < 4; ++u) {
          hi[u] = f2bf(f[u]);
          lo[u] = f2bf(f[u] - bf2f(hi[u]));
        }
        *(unsigned*)&Kh[r][c0 + q4*4]     = (unsigned)hi[0] | ((unsigned)hi[1] << 16);
        *(unsigned*)&Kh[r][c0 + q4*4 + 2] = (unsigned)hi[2] | ((unsigned)hi[3] << 16);
        *(unsigned*)&Kl[r][c0 + q4*4]     = (unsigned)lo[0] | ((unsigned)lo[1] << 16);
        *(unsigned*)&Kl[r][c0 + q4*4 + 2] = (unsigned)lo[2] | ((unsigned)lo[3] << 16);
      }
    }
    __syncthreads();
    f32x4 acc[4];
    #pragma unroll
    for (int nc = 0; nc < 4; ++nc) acc[nc] = (f32x4){0.f, 0.f, 0.f, 0.f};
    #pragma unroll
    for (int kb2 = 0; kb2 < 2; ++kb2) {
      bf16x8 ah = *(const bf16x8*)&Qh[wid*16 + (lane & 15)][kb2*32 + (lane >> 4)*8];
      bf16x8 al = *(const bf16x8*)&Ql[wid*16 + (lane & 15)][kb2*32 + (lane >> 4)*8];
      #pragma unroll
      for (int nc = 0; nc < 4; ++nc) {
        bf16x8 bh_ = *(const bf16x8*)&Kh[nc*16 + (lane & 15)][kb2*32 + (lane >> 4)*8];
        bf16x8 bl_ = *(const bf16x8*)&Kl[nc*16 + (lane & 15)][kb2*32 + (lane >> 4)*8];
        acc[nc] = __builtin_amdgcn_mfma_f32_16x16x32_bf16(ah, bh_, acc[nc], 0, 0, 0);
        acc[nc] = __builtin_amdgcn_mfma_f32_16x16x32_bf16(al, bh_, acc[nc], 0, 0, 0);
        acc[nc] = __builtin_amdgcn_mfma_f32_16x16x32_bf16(ah, bl_, acc[nc], 0, 0, 0);
      }
    }
    int rowbase = wid*16 + (lane >> 4)*4;
    #pragma unroll
    for (int nc = 0; nc < 4; ++nc) {
      int s = st * 64 + nc*16 + (lane & 15);
      #pragma unroll
      for (int qq = 0; qq < 4; ++qq) {
        int t_ = t0 + rowbase + qq;
        awb[(size_t)t_ * TT + s] = acc[nc][qq];
      }
    }
  }
}

// ---------------- row softmax in place: aw row -> probs (lower triangle only)
__global__ __launch_bounds__(256) void k_softmax(float* __restrict__ aw) {
  int bh = blockIdx.y;
  int wid = threadIdx.x >> 6, lane = threadIdx.x & 63;
  int t = blockIdx.x * 4 + wid;
  float* row = aw + ((size_t)bh * TT + t) * TT;
  float vals[16];
  float m = NEGF;
  #pragma unroll
  for (int i = 0; i < 16; ++i) {
    int j = lane + 64*i;
    vals[i] = (j <= t) ? row[j] : NEGF;
    m = fmaxf(m, vals[i]);
  }
  for (int o = 32; o; o >>= 1) m = fmaxf(m, __shfl_xor(m, o));
  float s = 0.f;
  #pragma unroll
  for (int i = 0; i < 16; ++i) {
    int j = lane + 64*i;
    if (j <= t) { vals[i] = expf(vals[i] - m); s += vals[i]; }
  }
  for (int o = 32; o; o >>= 1) s += __shfl_xor(s, o);
  float inv = 1.0f / s;
  #pragma unroll
  for (int i = 0; i < 16; ++i) {
    int j = lane + 64*i;
    if (j <= t) row[j] = vals[i] * inv;
  }
}

// ---------------- parallel init of heavy-hitter scores (p = probs)
__global__ __launch_bounds__(256) void k_init_acc(const float* __restrict__ p,
    float* __restrict__ initacc) {
  int bh = blockIdx.x;
  int c = threadIdx.x;
  float val = 0.f;
  if (c < HB) {
    const float* pb = p + (size_t)bh * TT * TT;
    for (int i = c; i < HB; ++i)
      val += pb[(size_t)i * TT + c];
  }
  initacc[(size_t)bh * 256 + c] = val;
}

// ---------------- wave-wide min over u32 via DPP (VALU path, no LDS)
#define DPP_HOP(ctrl)                                                        \
  {                                                                          \
    unsigned tt = (unsigned)__builtin_amdgcn_update_dpp(                     \
        (int)0xFFFFFFFFu, (int)x, (ctrl), 0xF, 0xF, false);                  \
    x = x < tt ? x : tt;                                                     \
  }
__device__ __forceinline__ unsigned wave_min_u32(unsigned x) {
  DPP_HOP(0x111)  // row_shr:1
  DPP_HOP(0x112)  // row_shr:2
  DPP_HOP(0x114)  // row_shr:4
  DPP_HOP(0x118)  // row_shr:8
  DPP_HOP(0x142)  // row_bcast:15
  DPP_HOP(0x143)  // row_bcast:31
  return (unsigned)__builtin_amdgcn_readlane((int)x, 63);
}

// global -> LDS direct DMA, 16B per lane
__device__ __forceinline__ void gload_lds16(const float* gsrc, float* ldst) {
  __builtin_amdgcn_global_load_lds(
      (const __attribute__((address_space(1))) unsigned int*)gsrc,
      (__attribute__((address_space(3))) unsigned int*)ldst,
      16, 0, 0);
}

// ---------------- serial heavy-hitter scan: SINGLE WAVE, TWO CHAINS (bh pair)
// Round-14 lesson: step time is structural (latency/clock-bound), so amortize
// it — one wave advances TWO independent bh chains per step. The two DPP
// reduces / read sets / selects are independent -> scheduler overlaps them.
//  * 8 DMA loads/step (4 per chain, A then B); INFLT2=6 rows in flight
//    (48 outstanding <= 63). Loop wait vmcnt(32) retires rows t AND t+1 for
//    both chains (reads target row t+1). Prologue wait vmcnt(40) retires HB.
//  * reads for row t+1 issue BEFORE select(t); evict-candidate read covers
//    both select outcomes; cndmask patch afterward.
//  * counted lgkmcnt(10) allows this iteration's 10 reads outstanding.
//  * no flags, no cross-wave handshake: only vmcnt/lgkm waits (no deadlock).
__global__ __launch_bounds__(64) void k_scan(const float* __restrict__ p,
    const float* __restrict__ initacc, int* __restrict__ evict_g) {
  int bhA = blockIdx.x * 2, bhB = bhA + 1;
  int lane = threadIdx.x;
  const float* pA = p + (size_t)bhA * TT * TT;
  const float* pB = p + (size_t)bhB * TT * TT;
  __shared__ float ringA[RING2][TT];
  __shared__ float ringB[RING2][TT];
  __shared__ int evA[TT];
  __shared__ int evB[TT];
  for (int i = lane; i < TT; i += 64) { evA[i] = 0x7fffffff; evB[i] = 0x7fffffff; }

  bool act2 = lane < (HB - 128);   // lane < 25
  int aC0 = lane, aC1 = 64 + lane, aC2 = act2 ? (128 + lane) : 0;
  int bC0 = lane, bC1 = 64 + lane, bC2 = act2 ? (128 + lane) : 0;
  float aS0 = initacc[(size_t)bhA * 256 + lane];
  float aS1 = initacc[(size_t)bhA * 256 + 64 + lane];
  float aS2 = act2 ? initacc[(size_t)bhA * 256 + 128 + lane] : 0.f;
  float bS0 = initacc[(size_t)bhB * 256 + lane];
  float bS1 = initacc[(size_t)bhB * 256 + 64 + lane];
  float bS2 = act2 ? initacc[(size_t)bhB * 256 + 128 + lane] : 0.f;

  unsigned baseA = (unsigned)(size_t)(lds_float*)&ringA[0][0];
  unsigned baseB = (unsigned)(size_t)(lds_float*)&ringB[0][0];

  // prologue: rows HB..HB+5 for both chains, interleaved A,B (48 loads)
  #pragma unroll
  for (int r = 0; r < INFLT2; ++r) {
    const float* sA = pA + (size_t)(HB + r) * TT;
    float* dA = ringA[(HB + r) & (RING2 - 1)];
    #pragma unroll
    for (int j = 0; j < 4; ++j) gload_lds16(sA + j * 256 + lane * 4, dA + j * 256);
    const float* sB = pB + (size_t)(HB + r) * TT;
    float* dB = ringB[(HB + r) & (RING2 - 1)];
    #pragma unroll
    for (int j = 0; j < 4; ++j) gload_lds16(sB + j * 256 + lane * 4, dB + j * 256);
  }

  float rA0, rA1, rA2, rAd, rAe, rB0, rB1, rB2, rBd, rBe;
  {
    unsigned sA = baseA + (unsigned)((HB & (RING2 - 1)) * (TT * 4));
    unsigned sB = baseB + (unsigned)((HB & (RING2 - 1)) * (TT * 4));
    unsigned a0 = sA + (unsigned)aC0 * 4, a1 = sA + (unsigned)aC1 * 4,
             a2 = sA + (unsigned)aC2 * 4, ad = sA + (unsigned)HB * 4,
             ae = sA + (unsigned)(HB - 1) * 4;
    unsigned b0 = sB + (unsigned)bC0 * 4, b1 = sB + (unsigned)bC1 * 4,
             b2 = sB + (unsigned)bC2 * 4, bd = sB + (unsigned)HB * 4,
             be = sB + (unsigned)(HB - 1) * 4;
    asm volatile("s_waitcnt vmcnt(40)");   // rows HB (A+B) landed
    asm volatile(
      "ds_read_b32 %0, %10\n\t"
      "ds_read_b32 %1, %11\n\t"
      "ds_read_b32 %2, %12\n\t"
      "ds_read_b32 %3, %13\n\t"
      "ds_read_b32 %4, %14\n\t"
      "ds_read_b32 %5, %15\n\t"
      "ds_read_b32 %6, %16\n\t"
      "ds_read_b32 %7, %17\n\t"
      "ds_read_b32 %8, %18\n\t"
      "ds_read_b32 %9, %19"
      : "=&v"(rA0), "=&v"(rA1), "=&v"(rA2), "=&v"(rAd), "=&v"(rAe),
        "=&v"(rB0), "=&v"(rB1), "=&v"(rB2), "=&v"(rBd), "=&v"(rBe)
      : "v"(a0), "v"(a1), "v"(a2), "v"(ad), "v"(ae),
        "v"(b0), "v"(b1), "v"(b2), "v"(bd), "v"(be));
  }
  bool aE0p = false, aE1p = false, aE2p = false;
  bool bE0p = false, bE1p = false, bE2p = false;

  for (int t = HB; t < TT; ++t) {
    int tn = (t + 1 < TT) ? (t + 1) : (TT - 1);   // clamped garbage re-read at tail
    // (1) rows t and t+1 landed for both chains (retire oldest 16 of 48)
    asm volatile("s_waitcnt vmcnt(32)");
    // (2) reads for row t+1: pre-select cols + diag + evict-candidate, both chains
    float nA0, nA1, nA2, nAd, nAe, nB0, nB1, nB2, nBd, nBe;
    {
      unsigned sA = baseA + (unsigned)((tn & (RING2 - 1)) * (TT * 4));
      unsigned sB = baseB + (unsigned)((tn & (RING2 - 1)) * (TT * 4));
      unsigned a0 = sA + (unsigned)aC0 * 4, a1 = sA + (unsigned)aC1 * 4,
               a2 = sA + (unsigned)aC2 * 4, ad = sA + (unsigned)tn * 4,
               ae = sA + (unsigned)t * 4;
      unsigned b0 = sB + (unsigned)bC0 * 4, b1 = sB + (unsigned)bC1 * 4,
               b2 = sB + (unsigned)bC2 * 4, bd = sB + (unsigned)tn * 4,
               be = sB + (unsigned)t * 4;
      asm volatile(
        "ds_read_b32 %0, %10\n\t"
        "ds_read_b32 %1, %11\n\t"
        "ds_read_b32 %2, %12\n\t"
        "ds_read_b32 %3, %13\n\t"
        "ds_read_b32 %4, %14\n\t"
        "ds_read_b32 %5, %15\n\t"
        "ds_read_b32 %6, %16\n\t"
        "ds_read_b32 %7, %17\n\t"
        "ds_read_b32 %8, %18\n\t"
        "ds_read_b32 %9, %19"
        : "=&v"(nA0), "=&v"(nA1), "=&v"(nA2), "=&v"(nAd), "=&v"(nAe),
          "=&v"(nB0), "=&v"(nB1), "=&v"(nB2), "=&v"(nBd), "=&v"(nBe)
        : "v"(a0), "v"(a1), "v"(a2), "v"(ad), "v"(ae),
          "v"(b0), "v"(b1), "v"(b2), "v"(bd), "v"(be));
    }
    // (3) DMA row t+6 for both chains (exactly 8 loads/step keeps the invariant)
    {
      int rn = t + INFLT2;
      int rsrc = rn < TT ? rn : TT - 1;
      const float* sA = pA + (size_t)rsrc * TT;
      float* dA = ringA[rn & (RING2 - 1)];
      #pragma unroll
      for (int j = 0; j < 4; ++j) gload_lds16(sA + j * 256 + lane * 4, dA + j * 256);
      const float* sB = pB + (size_t)rsrc * TT;
      float* dB = ringB[rn & (RING2 - 1)];
      #pragma unroll
      for (int j = 0; j < 4; ++j) gload_lds16(sB + j * 256 + lane * 4, dB + j * 256);
    }
    // (4) reduces for both chains (independent -> ILP across the DPP chains)
    unsigned aB0 = __float_as_uint(aS0);
    unsigned aB1 = __float_as_uint(aS1);
    unsigned aB2 = act2 ? __float_as_uint(aS2) : 0xFFFFFFFFu;
    unsigned bB0 = __float_as_uint(bS0);
    unsigned bB1 = __float_as_uint(bS1);
    unsigned bB2 = act2 ? __float_as_uint(bS2) : 0xFFFFFFFFu;
    unsigned aMn = aB0 < aB1 ? aB0 : aB1; aMn = aMn < aB2 ? aMn : aB2;
    unsigned bMn = bB0 < bB1 ? bB0 : bB1; bMn = bMn < bB2 ? bMn : bB2;
    unsigned aMst = wave_min_u32(aMn);
    unsigned bMst = wave_min_u32(bMn);
    bool aM0 = (aB0 == aMst), aM1 = (aB1 == aMst), aM2 = act2 && (aB2 == aMst);
    bool bM0 = (bB0 == bMst), bM1 = (bB1 == bMst), bM2 = act2 && (bB2 == bMst);
    int aL = (int)aM0 + (int)aM1 + (int)aM2;
    int bL = (int)bM0 + (int)bM1 + (int)bM2;
    ull aBal1 = __ballot(aL >= 1), aBal2 = __ballot(aL >= 2);
    ull bBal1 = __ballot(bL >= 1), bBal2 = __ballot(bL >= 2);
    bool aE0, aE1, aE2, bE0, bE1, bE2;
    if (aBal2 == 0 && __popcll(aBal1) == 1) {
      aE0 = aM0; aE1 = aM1; aE2 = aM2;
    } else {
      unsigned c0k = aM0 ? (unsigned)(1023 - aC0) : 0xFFFFFFFFu;
      unsigned c1k = aM1 ? (unsigned)(1023 - aC1) : 0xFFFFFFFFu;
      unsigned c2k = aM2 ? (unsigned)(1023 - aC2) : 0xFFFFFFFFu;
      unsigned cm = c0k < c1k ? c0k : c1k; cm = cm < c2k ? cm : c2k;
      int cstar = 1023 - (int)wave_min_u32(cm);
      aE0 = aM0 && (aC0 == cstar);
      aE1 = aM1 && (aC1 == cstar);
      aE2 = aM2 && (aC2 == cstar);
    }
    if (bBal2 == 0 && __popcll(bBal1) == 1) {
      bE0 = bM0; bE1 = bM1; bE2 = bM2;
    } else {
      unsigned c0k = bM0 ? (unsigned)(1023 - bC0) : 0xFFFFFFFFu;
      unsigned c1k = bM1 ? (unsigned)(1023 - bC1) : 0xFFFFFFFFu;
      unsigned c2k = bM2 ? (unsigned)(1023 - bC2) : 0xFFFFFFFFu;
      unsigned cm = c0k < c1k ? c0k : c1k; cm = cm < c2k ? cm : c2k;
      int cstar = 1023 - (int)wave_min_u32(cm);
      bE0 = bM0 && (bC0 == cstar);
      bE1 = bM1 && (bC1 == cstar);
      bE2 = bM2 && (bC2 == cstar);
    }
    // (5) counted wait: allow this iteration's 10 reads outstanding -> the
    // previous iteration's reads (rA*/rB*) are retired. Free in steady state.
    asm volatile("s_waitcnt lgkmcnt(10)");
    __builtin_amdgcn_sched_barrier(0);
    // patch: slot evicted at t-1 has col t-1 -> its row-t value is the
    // evict-candidate read (rAe / rBe)
    float pA0 = aE0p ? rAe : rA0;
    float pA1 = aE1p ? rAe : rA1;
    float pA2 = aE2p ? rAe : rA2;
    float pB0 = bE0p ? rBe : rB0;
    float pB1 = bE1p ? rBe : rB1;
    float pB2 = bE2p ? rBe : rB2;
    // (6) selects
    if (aE0) { evA[aC0] = t; aC0 = t; aS0 = rAd; } else aS0 += pA0;
    if (aE1) { evA[aC1] = t; aC1 = t; aS1 = rAd; } else aS1 += pA1;
    if (act2) {
      if (aE2) { evA[aC2] = t; aC2 = t; aS2 = rAd; } else aS2 += pA2;
    }
    if (bE0) { evB[bC0] = t; bC0 = t; bS0 = rBd; } else bS0 += pB0;
    if (bE1) { evB[bC1] = t; bC1 = t; bS1 = rBd; } else bS1 += pB1;
    if (act2) {
      if (bE2) { evB[bC2] = t; bC2 = t; bS2 = rBd; } else bS2 += pB2;
    }
    __builtin_amdgcn_sched_barrier(0);   // pin ev writes before next reads
    aE0p = aE0; aE1p = aE1; aE2p = aE2;
    bE0p = bE0; bE1p = bE1; bE2p = bE2;
    rA0 = nA0; rA1 = nA1; rA2 = nA2; rAd = nAd; rAe = nAe;
    rB0 = nB0; rB1 = nB1; rB2 = nB2; rBd = nBd; rBe = nBe;
  }

  asm volatile("s_waitcnt lgkmcnt(0)");
  {
    int4* dA = (int4*)(evict_g + (size_t)bhA * TT);
    int4* dB = (int4*)(evict_g + (size_t)bhB * TT);
    const int4* sA = (const int4*)evA;
    const int4* sB = (const int4*)evB;
    #pragma unroll
    for (int i = 0; i < 4; ++i) {
      dA[lane + 64 * i] = sA[lane + 64 * i];
      dB[lane + 64 * i] = sB[lane + 64 * i];
    }
  }
}

// ---------------- fused mask + renorm + PV via bf16 MFMA
__global__ __launch_bounds__(256) void k_pv(const float* __restrict__ p,
    const int* __restrict__ evict_g, const ushort* __restrict__ vbf,
    float* __restrict__ ao) {
  int bh = blockIdx.y, tt = blockIdx.x;
  int tid = threadIdx.x, lane = tid & 63, wid = tid >> 6;
  int t0 = tt * 64;
  __shared__ ushort PA[64][72];   // masked bf16 P tile
  __shared__ ushort VT[64][72];   // V tile transposed: VT[d][s]
  __shared__ float rowsum[64];
  __shared__ int et[TT];
  ((int4*)et)[tid] = ((const int4*)(evict_g + (size_t)bh * TT))[tid];
  if (tid < 64) rowsum[tid] = 0.f;
  const float* pb = p + ((size_t)bh * TT + t0) * TT;
  const ushort* vb = vbf + (size_t)bh * TT * DD;

  f32x4 acc[4];
  #pragma unroll
  for (int nc = 0; nc < 4; ++nc) acc[nc] = (f32x4){0.f, 0.f, 0.f, 0.f};

  int r = tid >> 2;
  int c0 = (tid & 3) * 16;
  int tg = t0 + r;
  __syncthreads();

  for (int st = 0; st <= tt; ++st) {
    const float* prow = pb + (size_t)r * TT + st * 64 + c0;
    float part = 0.f;
    ushort tmp16[16];
    #pragma unroll
    for (int q4 = 0; q4 < 4; ++q4) {
      float4 pv4 = *(const float4*)(prow + q4 * 4);
      float vals[4] = {pv4.x, pv4.y, pv4.z, pv4.w};
      #pragma unroll
      for (int u = 0; u < 4; ++u) {
        int j = st * 64 + c0 + q4 * 4 + u;
        bool allow = (j <= tg) && ((et[j] > tg) || (j + RECW >= tg));
        float mv = allow ? vals[u] : 0.f;
        part += mv;
        tmp16[q4 * 4 + u] = f2bf(mv);
      }
    }
    #pragma unroll
    for (int w2 = 0; w2 < 8; ++w2) {
      unsigned pk = (unsigned)tmp16[w2 * 2] | ((unsigned)tmp16[w2 * 2 + 1] << 16);
      *(unsigned*)&PA[r][c0 + w2 * 2] = pk;
    }
    part += __shfl_xor(part, 1);
    part += __shfl_xor(part, 2);
    if ((tid & 3) == 0) rowsum[r] += part;
    {
      const unsigned* vrow32 = (const unsigned*)(vb + (size_t)(st * 64 + r) * DD + c0);
      #pragma unroll
      for (int u = 0; u < 8; ++u) {
        unsigned vv = vrow32[u];
        VT[c0 + u * 2][r] = (ushort)(vv & 0xFFFF);
        VT[c0 + u * 2 + 1][r] = (ushort)(vv >> 16);
      }
    }
    __syncthreads();
    #pragma unroll
    for (int kb = 0; kb < 2; ++kb) {
      bf16x8 af = *(const bf16x8*)&PA[wid * 16 + (lane & 15)][kb * 32 + (lane >> 4) * 8];
      #pragma unroll
      for (int nc = 0; nc < 4; ++nc) {
        bf16x8 bfr = *(const bf16x8*)&VT[nc * 16 + (lane & 15)][kb * 32 + (lane >> 4) * 8];
        acc[nc] = __builtin_amdgcn_mfma_f32_16x16x32_bf16(af, bfr, acc[nc], 0, 0, 0);
      }
    }
    __syncthreads();
  }

  int b_ = bh >> 4, h_ = bh & 15;
  int rl = wid * 16 + (lane >> 4) * 4;
  #pragma unroll
  for (int nc = 0; nc < 4; ++nc) {
    int d = nc * 16 + (lane & 15);
    #pragma unroll
    for (int qq = 0; qq < 4; ++qq) {
      int rr = rl + qq;
      float outv = acc[nc][qq] / rowsum[rr];
      ao[((size_t)b_ * TT + (t0 + rr)) * EE + h_ * DD + d] = outv;
    }
  }
}

extern "C" void kernel_launch(void* const* d_in, const int* in_sizes, int n_in,
                              void* d_out, int out_size, void* d_ws, size_t ws_size,
                              hipStream_t stream) {
  const float* hs = (const float*)d_in[0];
  const float* Wq = (const float*)d_in[2];
  const float* bq = (const float*)d_in[3];
  const float* Wk = (const float*)d_in[4];
  const float* bk = (const float*)d_in[5];
  const float* Wv = (const float*)d_in[6];
  const float* bv = (const float*)d_in[7];
  const float* Wo = (const float*)d_in[8];
  const float* bo = (const float*)d_in[9];
  float* out = (float*)d_out;

  float* ws = (float*)d_ws;
  float* q  = ws + OFF_Q;
  float* k  = ws + OFF_K;
  float* v  = ws + OFF_V;     // holds bf16 V (ushort)
  float* aw = ws + OFF_AW;    // becomes probs after k_softmax
  float* ao = ws + OFF_AO;
  float* initacc = ws + OFF_END;
  int* evict = (int*)(ws + OFF_END + (size_t)BHN * 256);

  dim3 gproj(16, 32);
  k_pmm<<<gproj, 256, 0, stream>>>(hs, Wq, bq, q, 0.125f, 1);
  k_pmm<<<gproj, 256, 0, stream>>>(hs, Wk, bk, k, 1.0f, 1);
  k_pmm<<<gproj, 256, 0, stream>>>(hs, Wv, bv, v, 1.0f, 2);   // bf16 head-split

  dim3 gqk(16, BHN);
  k_qk_mfma<<<gqk, 256, 0, stream>>>(q, k, aw);

  dim3 grs(TT/4, BHN);
  k_softmax<<<grs, 256, 0, stream>>>(aw);

  k_init_acc<<<BHN, 256, 0, stream>>>(aw, initacc);

  k_scan<<<BHN/2, 64, 0, stream>>>(aw, initacc, evict);

  dim3 gpv(16, BHN);
  k_pv<<<gpv, 256, 0, stream>>>(aw, evict, (const ushort*)v, ao);

  dim3 gout(16, 32);
  k_pmm<<<gout, 256, 0, stream>>>(ao, Wo, bo, out, 1.0f, 0);
}

// Round 16
// 542.814 us; speedup vs baseline: 1.4116x; 1.4116x over previous
//
#include <hip/hip_runtime.h>
#include <hip/hip_bf16.h>
#include <stdint.h>

#define TT 1024
#define EE 1024
#define HH 16
#define DD 64
#define BHN 32
#define HB 153
#define RECW 102
#define RING 16
#define INFLT 8
#define NEGF (-3.4028234663852886e38f)

typedef unsigned long long ull;
typedef __attribute__((ext_vector_type(8))) short bf16x8;
typedef __attribute__((ext_vector_type(4))) float f32x4;
typedef __attribute__((address_space(3))) float lds_float;

// workspace layout (float element offsets)
#define OFF_Q  ((size_t)0)
#define OFF_K  (OFF_Q + (size_t)BHN*TT*DD)
#define OFF_V  (OFF_K + (size_t)BHN*TT*DD)   // reused as bf16 (ushort) buffer
#define OFF_AW (OFF_V + (size_t)BHN*TT*DD)
#define OFF_M  (OFF_AW + (size_t)BHN*TT*TT)
#define OFF_S  (OFF_M + (size_t)BHN*TT)
#define OFF_AO (OFF_S + (size_t)BHN*TT)
#define OFF_END (OFF_AO + (size_t)BHN*TT*DD)
// after OFF_END: initacc float[BHN*256], evict int[BHN*1024]

__device__ __forceinline__ ushort f2bf(float x) {
  unsigned u = __float_as_uint(x);
  u = (u + 0x7FFF + ((u >> 16) & 1)) >> 16;   // RNE
  return (ushort)u;
}
__device__ __forceinline__ float bf2f(ushort h) {
  return __uint_as_float((unsigned)h << 16);
}

// ---------------- split-bf16 MFMA GEMM body: Y = (X @ W + b) * scale
// mode: 0 = flat f32, 1 = headsplit f32, 2 = headsplit bf16
__device__ __forceinline__ void gemm_body(const float* __restrict__ X,
    const float* __restrict__ W, const float* __restrict__ bias,
    float* __restrict__ Y, float scale, int mode, int bx, int by) {
  __shared__ ushort Ah[64][72], Al[64][72];   // X tile hi/lo: [row][k]
  __shared__ ushort Bh[64][72], Bl[64][72];   // W tile hi/lo TRANSPOSED: [col][k]
  int tid = threadIdx.x, lane = tid & 63, wid = tid >> 6;
  int r = tid >> 2, c0 = (tid & 3) * 16;
  int r0 = by * 64, n0 = bx * 64;

  f32x4 acc[4];
  #pragma unroll
  for (int nc = 0; nc < 4; ++nc) acc[nc] = (f32x4){0.f, 0.f, 0.f, 0.f};

  for (int k0 = 0; k0 < EE; k0 += 64) {
    __syncthreads();
    {
      const float4* xs = (const float4*)(X + (size_t)(r0 + r) * EE + k0 + c0);
      #pragma unroll
      for (int q4 = 0; q4 < 4; ++q4) {
        float4 v = xs[q4];
        float f[4] = {v.x, v.y, v.z, v.w};
        ushort hi[4], lo[4];
        #pragma unroll
        for (int u = 0; u < 4; ++u) {
          hi[u] = f2bf(f[u]);
          lo[u] = f2bf(f[u] - bf2f(hi[u]));
        }
        *(unsigned*)&Ah[r][c0 + q4*4]     = (unsigned)hi[0] | ((unsigned)hi[1] << 16);
        *(unsigned*)&Ah[r][c0 + q4*4 + 2] = (unsigned)hi[2] | ((unsigned)hi[3] << 16);
        *(unsigned*)&Al[r][c0 + q4*4]     = (unsigned)lo[0] | ((unsigned)lo[1] << 16);
        *(unsigned*)&Al[r][c0 + q4*4 + 2] = (unsigned)lo[2] | ((unsigned)lo[3] << 16);
      }
    }
    {
      const float4* wsrc = (const float4*)(W + (size_t)(k0 + r) * EE + n0 + c0);
      #pragma unroll
      for (int q4 = 0; q4 < 4; ++q4) {
        float4 v = wsrc[q4];
        float f[4] = {v.x, v.y, v.z, v.w};
        #pragma unroll
        for (int u = 0; u < 4; ++u) {
          ushort hi = f2bf(f[u]);
          ushort lo = f2bf(f[u] - bf2f(hi));
          int c = c0 + q4*4 + u;
          Bh[c][r] = hi;
          Bl[c][r] = lo;
        }
      }
    }
    __syncthreads();
    #pragma unroll
    for (int kb = 0; kb < 2; ++kb) {
      bf16x8 ah = *(const bf16x8*)&Ah[wid*16 + (lane & 15)][kb*32 + (lane >> 4)*8];
      bf16x8 al = *(const bf16x8*)&Al[wid*16 + (lane & 15)][kb*32 + (lane >> 4)*8];
      #pragma unroll
      for (int nc = 0; nc < 4; ++nc) {
        bf16x8 bh_ = *(const bf16x8*)&Bh[nc*16 + (lane & 15)][kb*32 + (lane >> 4)*8];
        bf16x8 bl_ = *(const bf16x8*)&Bl[nc*16 + (lane & 15)][kb*32 + (lane >> 4)*8];
        acc[nc] = __builtin_amdgcn_mfma_f32_16x16x32_bf16(ah, bh_, acc[nc], 0, 0, 0);
        acc[nc] = __builtin_amdgcn_mfma_f32_16x16x32_bf16(al, bh_, acc[nc], 0, 0, 0);
        acc[nc] = __builtin_amdgcn_mfma_f32_16x16x32_bf16(ah, bl_, acc[nc], 0, 0, 0);
      }
    }
  }

  int rowbase = wid*16 + (lane >> 4)*4;
  #pragma unroll
  for (int nc = 0; nc < 4; ++nc) {
    int c = n0 + nc*16 + (lane & 15);
    float bv = bias[c];
    #pragma unroll
    for (int qq = 0; qq < 4; ++qq) {
      int rr = r0 + rowbase + qq;
      float val = (acc[nc][qq] + bv) * scale;
      int b_ = rr >> 10, t_ = rr & 1023, h_ = c >> 6, d_ = c & 63;
      if (mode == 1) {
        Y[(((size_t)(b_*HH + h_) * TT) + t_) * DD + d_] = val;
      } else if (mode == 2) {
        ((ushort*)Y)[(((size_t)(b_*HH + h_) * TT) + t_) * DD + d_] = f2bf(val);
      } else {
        Y[(size_t)rr * EE + c] = val;
      }
    }
  }
}

// fused Q/K/V projections: blockIdx.z selects target
__global__ __launch_bounds__(256) void k_qkv(const float* __restrict__ X,
    const float* __restrict__ Wq, const float* __restrict__ bq,
    const float* __restrict__ Wk, const float* __restrict__ bk,
    const float* __restrict__ Wv, const float* __restrict__ bv,
    float* __restrict__ q, float* __restrict__ k, float* __restrict__ v) {
  int z = blockIdx.z;
  if (z == 0)      gemm_body(X, Wq, bq, q, 0.125f, 1, blockIdx.x, blockIdx.y);
  else if (z == 1) gemm_body(X, Wk, bk, k, 1.0f,   1, blockIdx.x, blockIdx.y);
  else             gemm_body(X, Wv, bv, v, 1.0f,   2, blockIdx.x, blockIdx.y);
}

__global__ __launch_bounds__(256) void k_out(const float* __restrict__ X,
    const float* __restrict__ W, const float* __restrict__ bias,
    float* __restrict__ Y) {
  gemm_body(X, W, bias, Y, 1.0f, 0, blockIdx.x, blockIdx.y);
}

// ---------------- batched QK^T via split-bf16 MFMA (lower-triangle tiles)
__global__ __launch_bounds__(256) void k_qk_mfma(const float* __restrict__ q,
    const float* __restrict__ k, float* __restrict__ aw) {
  int bh = blockIdx.y, tt = blockIdx.x;
  int t0 = tt * 64;
  int tid = threadIdx.x, lane = tid & 63, wid = tid >> 6;
  int r = tid >> 2, c0 = (tid & 3) * 16;
  __shared__ ushort Qh[64][72], Ql[64][72];
  __shared__ ushort Kh[64][72], Kl[64][72];
  const float* qb = q + (size_t)bh * TT * DD;
  const float* kb = k + (size_t)bh * TT * DD;
  float* awb = aw + (size_t)bh * TT * TT;

  {
    const float4* xs = (const float4*)(qb + (size_t)(t0 + r) * DD + c0);
    #pragma unroll
    for (int q4 = 0; q4 < 4; ++q4) {
      float4 v = xs[q4];
      float f[4] = {v.x, v.y, v.z, v.w};
      ushort hi[4], lo[4];
      #pragma unroll
      for (int u = 0; u < 4; ++u) {
        hi[u] = f2bf(f[u]);
        lo[u] = f2bf(f[u] - bf2f(hi[u]));
      }
      *(unsigned*)&Qh[r][c0 + q4*4]     = (unsigned)hi[0] | ((unsigned)hi[1] << 16);
      *(unsigned*)&Qh[r][c0 + q4*4 + 2] = (unsigned)hi[2] | ((unsigned)hi[3] << 16);
      *(unsigned*)&Ql[r][c0 + q4*4]     = (unsigned)lo[0] | ((unsigned)lo[1] << 16);
      *(unsigned*)&Ql[r][c0 + q4*4 + 2] = (unsigned)lo[2] | ((unsigned)lo[3] << 16);
    }
  }

  for (int st = 0; st <= tt; ++st) {
    __syncthreads();
    {
      const float4* xs = (const float4*)(kb + (size_t)(st * 64 + r) * DD + c0);
      #pragma unroll
      for (int q4 = 0; q4 < 4; ++q4) {
        float4 v = xs[q4];
        float f[4] = {v.x, v.y, v.z, v.w};
        ushort hi[4], lo[4];
        #pragma unroll
        for (int u = 0; u < 4; ++u) {
          hi[u] = f2bf(f[u]);
          lo[u] = f2bf(f[u] - bf2f(hi[u]));
        }
        *(unsigned*)&Kh[r][c0 + q4*4]     = (unsigned)hi[0] | ((unsigned)hi[1] << 16);
        *(unsigned*)&Kh[r][c0 + q4*4 + 2] = (unsigned)hi[2] | ((unsigned)hi[3] << 16);
        *(unsigned*)&Kl[r][c0 + q4*4]     = (unsigned)lo[0] | ((unsigned)lo[1] << 16);
        *(unsigned*)&Kl[r][c0 + q4*4 + 2] = (unsigned)lo[2] | ((unsigned)lo[3] << 16);
      }
    }
    __syncthreads();
    f32x4 acc[4];
    #pragma unroll
    for (int nc = 0; nc < 4; ++nc) acc[nc] = (f32x4){0.f, 0.f, 0.f, 0.f};
    #pragma unroll
    for (int kb2 = 0; kb2 < 2; ++kb2) {
      bf16x8 ah = *(const bf16x8*)&Qh[wid*16 + (lane & 15)][kb2*32 + (lane >> 4)*8];
      bf16x8 al = *(const bf16x8*)&Ql[wid*16 + (lane & 15)][kb2*32 + (lane >> 4)*8];
      #pragma unroll
      for (int nc = 0; nc < 4; ++nc) {
        bf16x8 bh_ = *(const bf16x8*)&Kh[nc*16 + (lane & 15)][kb2*32 + (lane >> 4)*8];
        bf16x8 bl_ = *(const bf16x8*)&Kl[nc*16 + (lane & 15)][kb2*32 + (lane >> 4)*8];
        acc[nc] = __builtin_amdgcn_mfma_f32_16x16x32_bf16(ah, bh_, acc[nc], 0, 0, 0);
        acc[nc] = __builtin_amdgcn_mfma_f32_16x16x32_bf16(al, bh_, acc[nc], 0, 0, 0);
        acc[nc] = __builtin_amdgcn_mfma_f32_16x16x32_bf16(ah, bl_, acc[nc], 0, 0, 0);
      }
    }
    int rowbase = wid*16 + (lane >> 4)*4;
    #pragma unroll
    for (int nc = 0; nc < 4; ++nc) {
      int s = st * 64 + nc*16 + (lane & 15);
      #pragma unroll
      for (int qq = 0; qq < 4; ++qq) {
        int t_ = t0 + rowbase + qq;
        awb[(size_t)t_ * TT + s] = acc[nc][qq];
      }
    }
  }
}

// ---------------- row softmax in place: aw row -> probs (lower triangle only)
__global__ __launch_bounds__(256) void k_softmax(float* __restrict__ aw) {
  int bh = blockIdx.y;
  int wid = threadIdx.x >> 6, lane = threadIdx.x & 63;
  int t = blockIdx.x * 4 + wid;
  float* row = aw + ((size_t)bh * TT + t) * TT;
  float vals[16];
  float m = NEGF;
  #pragma unroll
  for (int i = 0; i < 16; ++i) {
    int j = lane + 64*i;
    vals[i] = (j <= t) ? row[j] : NEGF;
    m = fmaxf(m, vals[i]);
  }
  for (int o = 32; o; o >>= 1) m = fmaxf(m, __shfl_xor(m, o));
  float s = 0.f;
  #pragma unroll
  for (int i = 0; i < 16; ++i) {
    int j = lane + 64*i;
    if (j <= t) { vals[i] = expf(vals[i] - m); s += vals[i]; }
  }
  for (int o = 32; o; o >>= 1) s += __shfl_xor(s, o);
  float inv = 1.0f / s;
  #pragma unroll
  for (int i = 0; i < 16; ++i) {
    int j = lane + 64*i;
    if (j <= t) row[j] = vals[i] * inv;
  }
}

// ---------------- parallel init of heavy-hitter scores (p = probs)
__global__ __launch_bounds__(256) void k_init_acc(const float* __restrict__ p,
    float* __restrict__ initacc) {
  int bh = blockIdx.x;
  int c = threadIdx.x;
  float val = 0.f;
  if (c < HB) {
    const float* pb = p + (size_t)bh * TT * TT;
    for (int i = c; i < HB; ++i)
      val += pb[(size_t)i * TT + c];
  }
  initacc[(size_t)bh * 256 + c] = val;
}

// ---------------- wave-wide min over u32 via DPP (VALU path, no LDS)
#define DPP_HOP(ctrl)                                                        \
  {                                                                          \
    unsigned tt = (unsigned)__builtin_amdgcn_update_dpp(                     \
        (int)0xFFFFFFFFu, (int)x, (ctrl), 0xF, 0xF, false);                  \
    x = x < tt ? x : tt;                                                     \
  }
__device__ __forceinline__ unsigned wave_min_u32(unsigned x) {
  DPP_HOP(0x111)  // row_shr:1
  DPP_HOP(0x112)  // row_shr:2
  DPP_HOP(0x114)  // row_shr:4
  DPP_HOP(0x118)  // row_shr:8
  DPP_HOP(0x142)  // row_bcast:15
  DPP_HOP(0x143)  // row_bcast:31
  return (unsigned)__builtin_amdgcn_readlane((int)x, 63);
}

// global -> LDS direct DMA, 16B per lane
__device__ __forceinline__ void gload_lds16(const float* gsrc, float* ldst) {
  __builtin_amdgcn_global_load_lds(
      (const __attribute__((address_space(1))) unsigned int*)gsrc,
      (__attribute__((address_space(3))) unsigned int*)ldst,
      16, 0, 0);
}

// ---------------- serial heavy-hitter scan: SINGLE WAVE, self-paced DMA,
// read-ahead pipeline (round-14 form — best measured: ~274 us).
__global__ __launch_bounds__(64) void k_scan(const float* __restrict__ p,
    const float* __restrict__ initacc, int* __restrict__ evict_g) {
  int bh = blockIdx.x;
  int lane = threadIdx.x;
  const float* pb = p + (size_t)bh * TT * TT;
  __shared__ float ring[RING][TT];
  __shared__ int ev[TT];
  for (int i = lane; i < TT; i += 64) ev[i] = 0x7fffffff;

  bool act2 = lane < (HB - 128);   // lane < 25
  int col0 = lane, col1 = 64 + lane, col2 = act2 ? (128 + lane) : 0;
  float sc0 = initacc[(size_t)bh * 256 + lane];
  float sc1 = initacc[(size_t)bh * 256 + 64 + lane];
  float sc2 = act2 ? initacc[(size_t)bh * 256 + 128 + lane] : 0.f;

  unsigned ring_base = (unsigned)(size_t)(lds_float*)&ring[0][0];

  // prologue: issue rows HB..HB+7 (32 loads outstanding)
  #pragma unroll
  for (int r = 0; r < INFLT; ++r) {
    const float* srcrow = pb + (size_t)(HB + r) * TT;
    float* slotbase = ring[(HB + r) & (RING - 1)];
    #pragma unroll
    for (int j = 0; j < 4; ++j)
      gload_lds16(srcrow + j * 256 + lane * 4, slotbase + j * 256);
  }
  // row HB landed; issue its 5 reads (candidate read harmless/unused at t=HB)
  float r0, r1, r2, rd, re;
  {
    unsigned sbase = ring_base + (unsigned)((HB & (RING - 1)) * (TT * 4));
    unsigned a0 = sbase + (unsigned)col0 * 4;
    unsigned a1 = sbase + (unsigned)col1 * 4;
    unsigned a2 = sbase + (unsigned)col2 * 4;
    unsigned ad = sbase + (unsigned)HB * 4;
    unsigned ae = sbase + (unsigned)(HB - 1) * 4;
    asm volatile("s_waitcnt vmcnt(28)");
    asm volatile(
      "ds_read_b32 %0, %5\n\t"
      "ds_read_b32 %1, %6\n\t"
      "ds_read_b32 %2, %7\n\t"
      "ds_read_b32 %3, %8\n\t"
      "ds_read_b32 %4, %9"
      : "=&v"(r0), "=&v"(r1), "=&v"(r2), "=&v"(rd), "=&v"(re)
      : "v"(a0), "v"(a1), "v"(a2), "v"(ad), "v"(ae));
  }
  bool e0p = false, e1p = false, e2p = false;

  for (int t = HB; t < TT; ++t) {
    int tn = (t + 1 < TT) ? (t + 1) : (TT - 1);   // clamped: garbage re-read at tail
    // (1) ensure row t+1 landed (retire oldest 8 of 32 outstanding loads)
    asm volatile("s_waitcnt vmcnt(24)");
    // (2) issue reads for row t+1 at PRE-select cols + diag + evict-candidate
    float n0, n1, n2, nd, ne;
    {
      unsigned sbase = ring_base + (unsigned)((tn & (RING - 1)) * (TT * 4));
      unsigned a0 = sbase + (unsigned)col0 * 4;
      unsigned a1 = sbase + (unsigned)col1 * 4;
      unsigned a2 = sbase + (unsigned)col2 * 4;
      unsigned ad = sbase + (unsigned)tn * 4;
      unsigned ae = sbase + (unsigned)t * 4;
      asm volatile(
        "ds_read_b32 %0, %5\n\t"
        "ds_read_b32 %1, %6\n\t"
        "ds_read_b32 %2, %7\n\t"
        "ds_read_b32 %3, %8\n\t"
        "ds_read_b32 %4, %9"
        : "=&v"(n0), "=&v"(n1), "=&v"(n2), "=&v"(nd), "=&v"(ne)
        : "v"(a0), "v"(a1), "v"(a2), "v"(ad), "v"(ae));
    }
    // (3) issue DMA for row t+8 (exactly 4 loads/step keeps vmcnt invariant)
    {
      int rn = t + INFLT;
      int rsrc = rn < TT ? rn : TT - 1;
      const float* srcrow = pb + (size_t)rsrc * TT;
      float* slotbase = ring[rn & (RING - 1)];
      #pragma unroll
      for (int j = 0; j < 4; ++j)
        gload_lds16(srcrow + j * 256 + lane * 4, slotbase + j * 256);
    }
    // (4) reduce for step t (keys = scores BEFORE adding row t, as in reference)
    unsigned b0 = __float_as_uint(sc0);
    unsigned b1 = __float_as_uint(sc1);
    unsigned b2 = act2 ? __float_as_uint(sc2) : 0xFFFFFFFFu;
    unsigned mn = b0 < b1 ? b0 : b1; mn = mn < b2 ? mn : b2;
    unsigned mstar = wave_min_u32(mn);
    bool m0 = (b0 == mstar), m1 = (b1 == mstar), m2 = act2 && (b2 == mstar);
    int lcl = (int)m0 + (int)m1 + (int)m2;
    ull bal1 = __ballot(lcl >= 1);
    ull bal2 = __ballot(lcl >= 2);
    bool e0, e1, e2;
    if (bal2 == 0 && __popcll(bal1) == 1) {
      e0 = m0; e1 = m1; e2 = m2;
    } else {
      unsigned c0k = m0 ? (unsigned)(1023 - col0) : 0xFFFFFFFFu;
      unsigned c1k = m1 ? (unsigned)(1023 - col1) : 0xFFFFFFFFu;
      unsigned c2k = m2 ? (unsigned)(1023 - col2) : 0xFFFFFFFFu;
      unsigned cm = c0k < c1k ? c0k : c1k; cm = cm < c2k ? cm : c2k;
      int cstar = 1023 - (int)wave_min_u32(cm);
      e0 = m0 && (col0 == cstar);
      e1 = m1 && (col1 == cstar);
      e2 = m2 && (col2 == cstar);
    }
    // (5) counted wait: allow this iteration's 5 reads outstanding; the
    // previous iteration's reads (r*) are proven retired. Free in steady state.
    asm volatile("s_waitcnt lgkmcnt(5)");
    __builtin_amdgcn_sched_barrier(0);
    // patch: slot evicted at t-1 moved to col t-1 -> its row-t value is re
    float rr0 = e0p ? re : r0;
    float rr1 = e1p ? re : r1;
    float rr2 = e2p ? re : r2;
    // (6) select
    if (e0) { ev[col0] = t; col0 = t; sc0 = rd; } else sc0 += rr0;
    if (e1) { ev[col1] = t; col1 = t; sc1 = rd; } else sc1 += rr1;
    if (act2) {
      if (e2) { ev[col2] = t; col2 = t; sc2 = rd; } else sc2 += rr2;
    }
    __builtin_amdgcn_sched_barrier(0);   // pin ev writes before next reads
    e0p = e0; e1p = e1; e2p = e2;
    r0 = n0; r1 = n1; r2 = n2; rd = nd; re = ne;
  }

  asm volatile("s_waitcnt lgkmcnt(0)");
  int4* dst4 = (int4*)(evict_g + (size_t)bh * TT);
  const int4* src4 = (const int4*)ev;
  #pragma unroll
  for (int i = 0; i < 4; ++i) dst4[lane + 64 * i] = src4[lane + 64 * i];
}

// ---------------- fused mask + renorm + PV via bf16 MFMA
__global__ __launch_bounds__(256) void k_pv(const float* __restrict__ p,
    const int* __restrict__ evict_g, const ushort* __restrict__ vbf,
    float* __restrict__ ao) {
  int bh = blockIdx.y, tt = blockIdx.x;
  int tid = threadIdx.x, lane = tid & 63, wid = tid >> 6;
  int t0 = tt * 64;
  __shared__ ushort PA[64][72];   // masked bf16 P tile
  __shared__ ushort VT[64][72];   // V tile transposed: VT[d][s]
  __shared__ float rowsum[64];
  __shared__ int et[TT];
  ((int4*)et)[tid] = ((const int4*)(evict_g + (size_t)bh * TT))[tid];
  if (tid < 64) rowsum[tid] = 0.f;
  const float* pb = p + ((size_t)bh * TT + t0) * TT;
  const ushort* vb = vbf + (size_t)bh * TT * DD;

  f32x4 acc[4];
  #pragma unroll
  for (int nc = 0; nc < 4; ++nc) acc[nc] = (f32x4){0.f, 0.f, 0.f, 0.f};

  int r = tid >> 2;
  int c0 = (tid & 3) * 16;
  int tg = t0 + r;
  __syncthreads();

  for (int st = 0; st <= tt; ++st) {
    const float* prow = pb + (size_t)r * TT + st * 64 + c0;
    float part = 0.f;
    ushort tmp16[16];
    #pragma unroll
    for (int q4 = 0; q4 < 4; ++q4) {
      float4 pv4 = *(const float4*)(prow + q4 * 4);
      float vals[4] = {pv4.x, pv4.y, pv4.z, pv4.w};
      #pragma unroll
      for (int u = 0; u < 4; ++u) {
        int j = st * 64 + c0 + q4 * 4 + u;
        bool allow = (j <= tg) && ((et[j] > tg) || (j + RECW >= tg));
        float mv = allow ? vals[u] : 0.f;
        part += mv;
        tmp16[q4 * 4 + u] = f2bf(mv);
      }
    }
    #pragma unroll
    for (int w2 = 0; w2 < 8; ++w2) {
      unsigned pk = (unsigned)tmp16[w2 * 2] | ((unsigned)tmp16[w2 * 2 + 1] << 16);
      *(unsigned*)&PA[r][c0 + w2 * 2] = pk;
    }
    part += __shfl_xor(part, 1);
    part += __shfl_xor(part, 2);
    if ((tid & 3) == 0) rowsum[r] += part;
    {
      const unsigned* vrow32 = (const unsigned*)(vb + (size_t)(st * 64 + r) * DD + c0);
      #pragma unroll
      for (int u = 0; u < 8; ++u) {
        unsigned vv = vrow32[u];
        VT[c0 + u * 2][r] = (ushort)(vv & 0xFFFF);
        VT[c0 + u * 2 + 1][r] = (ushort)(vv >> 16);
      }
    }
    __syncthreads();
    #pragma unroll
    for (int kb = 0; kb < 2; ++kb) {
      bf16x8 af = *(const bf16x8*)&PA[wid * 16 + (lane & 15)][kb * 32 + (lane >> 4) * 8];
      #pragma unroll
      for (int nc = 0; nc < 4; ++nc) {
        bf16x8 bfr = *(const bf16x8*)&VT[nc * 16 + (lane & 15)][kb * 32 + (lane >> 4) * 8];
        acc[nc] = __builtin_amdgcn_mfma_f32_16x16x32_bf16(af, bfr, acc[nc], 0, 0, 0);
      }
    }
    __syncthreads();
  }

  int b_ = bh >> 4, h_ = bh & 15;
  int rl = wid * 16 + (lane >> 4) * 4;
  #pragma unroll
  for (int nc = 0; nc < 4; ++nc) {
    int d = nc * 16 + (lane & 15);
    #pragma unroll
    for (int qq = 0; qq < 4; ++qq) {
      int rr = rl + qq;
      float outv = acc[nc][qq] / rowsum[rr];
      ao[((size_t)b_ * TT + (t0 + rr)) * EE + h_ * DD + d] = outv;
    }
  }
}

extern "C" void kernel_launch(void* const* d_in, const int* in_sizes, int n_in,
                              void* d_out, int out_size, void* d_ws, size_t ws_size,
                              hipStream_t stream) {
  const float* hs = (const float*)d_in[0];
  const float* Wq = (const float*)d_in[2];
  const float* bq = (const float*)d_in[3];
  const float* Wk = (const float*)d_in[4];
  const float* bk = (const float*)d_in[5];
  const float* Wv = (const float*)d_in[6];
  const float* bv = (const float*)d_in[7];
  const float* Wo = (const float*)d_in[8];
  const float* bo = (const float*)d_in[9];
  float* out = (float*)d_out;

  float* ws = (float*)d_ws;
  float* q  = ws + OFF_Q;
  float* k  = ws + OFF_K;
  float* v  = ws + OFF_V;     // holds bf16 V (ushort)
  float* aw = ws + OFF_AW;    // becomes probs after k_softmax
  float* ao = ws + OFF_AO;
  float* initacc = ws + OFF_END;
  int* evict = (int*)(ws + OFF_END + (size_t)BHN * 256);

  dim3 gqkv(16, 32, 3);
  k_qkv<<<gqkv, 256, 0, stream>>>(hs, Wq, bq, Wk, bk, Wv, bv, q, k, v);

  dim3 gqk(16, BHN);
  k_qk_mfma<<<gqk, 256, 0, stream>>>(q, k, aw);

  dim3 grs(TT/4, BHN);
  k_softmax<<<grs, 256, 0, stream>>>(aw);

  k_init_acc<<<BHN, 256, 0, stream>>>(aw, initacc);

  k_scan<<<BHN, 64, 0, stream>>>(aw, initacc, evict);

  dim3 gpv(16, BHN);
  k_pv<<<gpv, 256, 0, stream>>>(aw, evict, (const ushort*)v, ao);

  dim3 gout(16, 32);
  k_out<<<gout, 256, 0, stream>>>(ao, Wo, bo, out);
}